// Round 1
// baseline (42.933 us; speedup 1.0000x reference)
//
#include <hip/hip_runtime.h>

// out[i,j,k] = sum_h X[i+1,h]*X[j+1,h]*Wp[h,k] + b[k]
// (symmetrization cancels the d-terms; prod_term is symmetric in i,j)

constexpr int Ld  = 384;   // sequence length of input
constexpr int Hd  = 768;   // hidden
constexpr int OUT = 382;   // output rows/cols (L-2)
constexpr int TILE = 32;   // output tile (i and j)
constexpr int HC   = 64;   // h chunk staged in LDS
constexpr int SPLITK = 4;  // h-splits across blockIdx.z
constexpr int HPER = Hd / SPLITK;  // 192

__global__ __launch_bounds__(256)
void pairhead_kernel(const float* __restrict__ X,
                     const float* __restrict__ W,
                     const float* __restrict__ bias,
                     float* __restrict__ out) {
  const int bi = blockIdx.y;
  const int bj = blockIdx.x;
  if (bj < bi) return;              // symmetry: only upper-triangular tiles
  const int z = blockIdx.z;

  __shared__ float sx[TILE][HC + 1];   // +1 pad: conflict-free scalar reads
  __shared__ float sy[TILE][HC + 1];
  __shared__ float sw[HC * 2];         // interleaved w0,w1 per h

  const int t  = threadIdx.x;          // 0..255
  const int i0 = bi * TILE, j0 = bj * TILE;
  const int ti = ((t >> 4) & 15) << 1; // 0,2,..,30
  const int tj = (t & 15) << 1;        // 0,2,..,30

  float acc[2][2][2] = {{{0.f, 0.f}, {0.f, 0.f}}, {{0.f, 0.f}, {0.f, 0.f}}};

  const int hbase = z * HPER;
  for (int h0 = hbase; h0 < hbase + HPER; h0 += HC) {
    __syncthreads();
    // stage sx/sy: 2048 floats each = 512 float4 loads each; 2 per thread each
    for (int u = t; u < TILE * HC / 4; u += 256) {
      const int r = u >> 4;
      const int c = (u & 15) * 4;
      const int gi = i0 + r;
      float4 v = make_float4(0.f, 0.f, 0.f, 0.f);
      if (gi < OUT) v = *reinterpret_cast<const float4*>(X + (size_t)(gi + 1) * Hd + h0 + c);
      sx[r][c] = v.x; sx[r][c + 1] = v.y; sx[r][c + 2] = v.z; sx[r][c + 3] = v.w;
      const int gj = j0 + r;
      float4 w4 = make_float4(0.f, 0.f, 0.f, 0.f);
      if (gj < OUT) w4 = *reinterpret_cast<const float4*>(X + (size_t)(gj + 1) * Hd + h0 + c);
      sy[r][c] = w4.x; sy[r][c + 1] = w4.y; sy[r][c + 2] = w4.z; sy[r][c + 3] = w4.w;
    }
    // stage w chunk: 128 contiguous floats (W rows h0..h0+63, both cols)
    if (t < 32) {
      float4 wv = *reinterpret_cast<const float4*>(W + h0 * 2 + t * 4);
      sw[t * 4] = wv.x; sw[t * 4 + 1] = wv.y; sw[t * 4 + 2] = wv.z; sw[t * 4 + 3] = wv.w;
    }
    __syncthreads();

    #pragma unroll 8
    for (int c = 0; c < HC; ++c) {
      const float w0 = sw[2 * c];
      const float w1 = sw[2 * c + 1];
      const float xi0 = sx[ti][c],     xi1 = sx[ti + 1][c];
      const float xj0 = sy[tj][c],     xj1 = sy[tj + 1][c];
      float p;
      p = xi0 * xj0; acc[0][0][0] += p * w0; acc[0][0][1] += p * w1;
      p = xi0 * xj1; acc[0][1][0] += p * w0; acc[0][1][1] += p * w1;
      p = xi1 * xj0; acc[1][0][0] += p * w0; acc[1][0][1] += p * w1;
      p = xi1 * xj1; acc[1][1][0] += p * w0; acc[1][1][1] += p * w1;
    }
  }

  const bool diag = (bi == bj);
  const float b0 = (z == 0) ? bias[0] : 0.f;
  const float b1 = (z == 0) ? bias[1] : 0.f;
  #pragma unroll
  for (int di = 0; di < 2; ++di) {
    #pragma unroll
    for (int dj = 0; dj < 2; ++dj) {
      const int i = i0 + ti + di;
      const int j = j0 + tj + dj;
      if (i >= OUT || j >= OUT) continue;
      const float v0 = acc[di][dj][0] + b0;
      const float v1 = acc[di][dj][1] + b1;
      atomicAdd(&out[((size_t)i * OUT + j) * 2 + 0], v0);
      atomicAdd(&out[((size_t)i * OUT + j) * 2 + 1], v1);
      if (!diag) {  // mirror: out[j,i] == out[i,j]
        atomicAdd(&out[((size_t)j * OUT + i) * 2 + 0], v0);
        atomicAdd(&out[((size_t)j * OUT + i) * 2 + 1], v1);
      }
    }
  }
}

extern "C" void kernel_launch(void* const* d_in, const int* in_sizes, int n_in,
                              void* d_out, int out_size, void* d_ws, size_t ws_size,
                              hipStream_t stream) {
  const float* X    = (const float*)d_in[0];  // (1,384,768) fp32
  // d_in[1] = sequence_lengths (unused by the reference output)
  const float* W    = (const float*)d_in[2];  // (1536,2) fp32; rows [0,768) = Wp
  const float* bias = (const float*)d_in[3];  // (2,)
  float* out = (float*)d_out;                 // (1,382,382,2) fp32

  hipMemsetAsync(out, 0, (size_t)out_size * sizeof(float), stream);
  dim3 grid((OUT + TILE - 1) / TILE, (OUT + TILE - 1) / TILE, SPLITK);
  pairhead_kernel<<<grid, dim3(256, 1, 1), 0, stream>>>(X, W, bias, out);
}

// Round 2
// 21.380 us; speedup vs baseline: 2.0081x; 2.0081x over previous
//
#include <hip/hip_runtime.h>

// out[i,j,k] = sum_h X[i+1,h]*X[j+1,h]*Wp[h,k] + b[k]
// (the (pred+pred^T)/2 symmetrization cancels the antisymmetric d-terms;
//  prod_term is symmetric => compute upper-triangular tiles, mirror-store)

constexpr int Hd   = 768;   // hidden
constexpr int OUT  = 382;   // output rows/cols (L-2)
constexpr int TILE = 16;    // output tile (i and j)
constexpr int NT   = 24;    // ceil(382/16)
constexpr int HC   = 256;   // h chunk staged in LDS
constexpr int STR  = HC + 4; // padded LDS row stride (floats)

__global__ __launch_bounds__(256)
void pairhead_kernel(const float* __restrict__ X,
                     const float* __restrict__ W,
                     const float* __restrict__ bias,
                     float* __restrict__ out) {
  const int bi = blockIdx.y;
  const int bj = blockIdx.x;
  if (bj < bi) return;             // symmetry: upper-triangular tiles only

  __shared__ float sx[TILE][STR];
  __shared__ float sy[TILE][STR];
  __shared__ float sw[HC * 2];     // interleaved w0,w1 per h

  const int t  = threadIdx.x;      // 0..255
  const int ti = t >> 4;           // row within tile
  const int tj = t & 15;           // col within tile
  const int i  = bi * TILE + ti;
  const int j  = bj * TILE + tj;

  float a0 = 0.f, a1 = 0.f;

  for (int h0 = 0; h0 < Hd; h0 += HC) {
    __syncthreads();
    // stage sx/sy: 16 rows x 256 cols = 1024 float4 each; 4 per thread each
    #pragma unroll
    for (int u = t; u < TILE * HC / 4; u += 256) {
      const int r = u >> 6;            // HC/4 = 64 float4 per row
      const int c = (u & 63) * 4;
      const int gi = bi * TILE + r;
      float4 v = make_float4(0.f, 0.f, 0.f, 0.f);
      if (gi < OUT) v = *reinterpret_cast<const float4*>(X + (size_t)(gi + 1) * Hd + h0 + c);
      *reinterpret_cast<float4*>(&sx[r][c]) = v;
      const int gj = bj * TILE + r;
      float4 w4 = make_float4(0.f, 0.f, 0.f, 0.f);
      if (gj < OUT) w4 = *reinterpret_cast<const float4*>(X + (size_t)(gj + 1) * Hd + h0 + c);
      *reinterpret_cast<float4*>(&sy[r][c]) = w4;
    }
    // stage W chunk: HC*2 = 512 floats = 128 float4
    if (t < 128) {
      float4 wv = *reinterpret_cast<const float4*>(W + h0 * 2 + t * 4);
      *reinterpret_cast<float4*>(&sw[t * 4]) = wv;
    }
    __syncthreads();

    #pragma unroll 16
    for (int c = 0; c < HC; ++c) {
      const float xi = sx[ti][c];
      const float xj = sy[tj][c];
      const float p  = xi * xj;
      a0 += p * sw[2 * c];
      a1 += p * sw[2 * c + 1];
    }
  }

  if (i < OUT && j < OUT) {
    const float b0 = bias[0], b1 = bias[1];
    const float v0 = a0 + b0, v1 = a1 + b1;
    *reinterpret_cast<float2*>(&out[((size_t)i * OUT + j) * 2]) = make_float2(v0, v1);
    if (bi != bj) {  // mirror tile (diagonal tiles already cover both orders)
      *reinterpret_cast<float2*>(&out[((size_t)j * OUT + i) * 2]) = make_float2(v0, v1);
    }
  }
}

extern "C" void kernel_launch(void* const* d_in, const int* in_sizes, int n_in,
                              void* d_out, int out_size, void* d_ws, size_t ws_size,
                              hipStream_t stream) {
  const float* X    = (const float*)d_in[0];  // (1,384,768) fp32
  // d_in[1] = sequence_lengths (dead: output is independent of it)
  const float* W    = (const float*)d_in[2];  // (1536,2) fp32; rows [0,768) = Wp
  const float* bias = (const float*)d_in[3];  // (2,)
  float* out = (float*)d_out;                 // (1,382,382,2) fp32

  dim3 grid(NT, NT, 1);
  pairhead_kernel<<<grid, dim3(256, 1, 1), 0, stream>>>(X, W, bias, out);
}